// Round 2
// baseline (155.919 us; speedup 1.0000x reference)
//
#include <hip/hip_runtime.h>

// Fused MLPKAN: layer0 (64->64, 4096 subnets 1-2-2-1) -> layer1 (64->16, 1024
// subnets), B=16384, fp32. One kernel: block = 16 batches, 4 waves.
//  - x tile staged in LDS (coalesced float4), hot-loop xv = ds_read broadcast
//  - layer0: wave handles 4 batches, lane = o (0..63); weights coalesced
//  - h written to LDS (stride 65 to break bank alias), __syncthreads
//  - layer1: lane = bs*16+o, each lane one (batch, o) pair
// Grid = 1024 blocks -> 4 blocks/CU -> 16 waves/CU (4 waves/SIMD TLP).

#define BATCH 16384
#define TB    16   // batches per block

__global__ __launch_bounds__(256) void kan_fused(
    const float* __restrict__ x,
    const float* __restrict__ A1, const float* __restrict__ a1,
    const float* __restrict__ A2, const float* __restrict__ a2,
    const float* __restrict__ A3, const float* __restrict__ a3,
    const float* __restrict__ B1, const float* __restrict__ c1,
    const float* __restrict__ B2, const float* __restrict__ c2,
    const float* __restrict__ B3, const float* __restrict__ c3,
    float* __restrict__ out)
{
    __shared__ float xs[TB][64];
    __shared__ float hs[TB][65];   // +1 pad: layer1 reads hs[b][i], 4 b's/wave

    const int t    = threadIdx.x;
    const int lane = t & 63;
    const int wave = t >> 6;
    const int bB0  = blockIdx.x * TB;

    // ---- stage x tile: 16x64 floats, one float4 per thread ----
    {
        const int flat = t * 4;                 // 0..1020
        const float4 v = *(const float4*)(x + bB0 * 64 + flat);
        xs[flat >> 6][flat & 63] = v.x;
        xs[flat >> 6][(flat & 63) + 1] = v.y;
        xs[flat >> 6][(flat & 63) + 2] = v.z;
        xs[flat >> 6][(flat & 63) + 3] = v.w;
    }
    __syncthreads();

    // ---- layer 0: lane = o, wave owns batches wb0..wb0+3 ----
    const int o   = lane;
    const int wb0 = wave * 4;
    float acc0[4] = {0.f, 0.f, 0.f, 0.f};
    float bsum0 = 0.f;

#pragma unroll 4
    for (int i = 0; i < 64; ++i) {
        const int n = (i << 6) + o;
        const float2 w1 = *(const float2*)(A1 + 2 * n);
        const float2 d1 = *(const float2*)(a1 + 2 * n);
        const float4 w2 = *(const float4*)(A2 + 4 * n);
        const float2 d2 = *(const float2*)(a2 + 2 * n);
        const float2 w3 = *(const float2*)(A3 + 2 * n);
        bsum0 += A3 == nullptr ? 0.f : a3[n];
#pragma unroll
        for (int j = 0; j < 4; ++j) {
            const float xv = xs[wb0 + j][i];    // lane-invariant -> broadcast
            float m0 = fmaxf(fmaf(xv, w1.x, d1.x), 0.f);
            float m1 = fmaxf(fmaf(xv, w1.y, d1.y), 0.f);
            float t0 = fmaxf(fmaf(w2.x, m0, fmaf(w2.y, m1, d2.x)), 0.f);
            float t1 = fmaxf(fmaf(w2.z, m0, fmaf(w2.w, m1, d2.y)), 0.f);
            acc0[j] = fmaf(w3.x, t0, acc0[j]);
            acc0[j] = fmaf(w3.y, t1, acc0[j]);
        }
    }
#pragma unroll
    for (int j = 0; j < 4; ++j)
        hs[wb0 + j][o] = acc0[j] + bsum0;       // 64 lanes consecutive: 2-way, free
    __syncthreads();

    // ---- layer 1: lane = bs*16 + o1; each lane one (batch, output) pair ----
    const int o1 = lane & 15;
    const int bs = lane >> 4;
    const int b  = wb0 + bs;
    float acc1  = 0.f;
    float bsum1 = 0.f;

#pragma unroll 4
    for (int i = 0; i < 64; ++i) {
        const int n = (i << 4) + o1;
        const float2 w1 = *(const float2*)(B1 + 2 * n);
        const float2 d1 = *(const float2*)(c1 + 2 * n);
        const float4 w2 = *(const float4*)(B2 + 4 * n);
        const float2 d2 = *(const float2*)(c2 + 2 * n);
        const float2 w3 = *(const float2*)(B3 + 2 * n);
        bsum1 += c3[n];
        const float xv = hs[b][i];              // stride-65 rows: 4 banks, ok
        float m0 = fmaxf(fmaf(xv, w1.x, d1.x), 0.f);
        float m1 = fmaxf(fmaf(xv, w1.y, d1.y), 0.f);
        float t0 = fmaxf(fmaf(w2.x, m0, fmaf(w2.y, m1, d2.x)), 0.f);
        float t1 = fmaxf(fmaf(w2.z, m0, fmaf(w2.w, m1, d2.y)), 0.f);
        acc1 = fmaf(w3.x, t0, acc1);
        acc1 = fmaf(w3.y, t1, acc1);
    }
    out[(bB0 + b) * 16 + o1] = acc1 + bsum1;    // 64 lanes = 64 consecutive floats
}

extern "C" void kernel_launch(void* const* d_in, const int* in_sizes, int n_in,
                              void* d_out, int out_size, void* d_ws, size_t ws_size,
                              hipStream_t stream) {
    const float* x     = (const float*)d_in[0];
    const float* l0_W1 = (const float*)d_in[1];
    const float* l0_b1 = (const float*)d_in[2];
    const float* l0_W2 = (const float*)d_in[3];
    const float* l0_b2 = (const float*)d_in[4];
    const float* l0_W3 = (const float*)d_in[5];
    const float* l0_b3 = (const float*)d_in[6];
    const float* l1_W1 = (const float*)d_in[7];
    const float* l1_b1 = (const float*)d_in[8];
    const float* l1_W2 = (const float*)d_in[9];
    const float* l1_b2 = (const float*)d_in[10];
    const float* l1_W3 = (const float*)d_in[11];
    const float* l1_b3 = (const float*)d_in[12];

    float* outp = (float*)d_out;

    dim3 blk(256);
    dim3 grid(BATCH / TB);   // 1024 blocks
    hipLaunchKernelGGL(kan_fused, grid, blk, 0, stream,
                       x,
                       l0_W1, l0_b1, l0_W2, l0_b2, l0_W3, l0_b3,
                       l1_W1, l1_b1, l1_W2, l1_b2, l1_W3, l1_b3,
                       outp);
}